// Round 10
// baseline (2060.887 us; speedup 1.0000x reference)
//
#include <hip/hip_runtime.h>

#define NN 100000
#define NE 1600000
#define INDIM 128
#define HID 64
#define NG 1024
#define NB 1563            // ceil(NN/64) buckets of 64 target nodes
#define SCB 256            // scatter blocks (private-region multisplit)
#define EPB ((NE + SCB - 1) / SCB)   // 6250 edges per scatter block
#define BN_EPS 1e-5f

typedef unsigned short u16;
typedef unsigned int u32;

__device__ __forceinline__ u16 f2bf(float f) {
    u32 u = __float_as_uint(f);
    u32 r = (u + 0x7fffu + ((u >> 16) & 1u)) >> 16;   // RNE
    return (u16)r;
}
__device__ __forceinline__ float bf2f(u32 b) {
    return __uint_as_float(b << 16);
}

// ---------------- graph preprocessing ----------------

// per-block bucket histogram (LDS only).
__global__ void k_hist(const int* __restrict__ col, int* __restrict__ hist, int E) {
    __shared__ int h[NB];
    int b = blockIdx.x;
    for (int i = threadIdx.x; i < NB; i += 256) h[i] = 0;
    __syncthreads();
    int s = b * EPB, e = min(s + EPB, E);
    for (int i = s + threadIdx.x; i < e; i += 256) {
        atomicAdd(&h[col[i] >> 6], 1);
    }
    __syncthreads();
    for (int i = threadIdx.x; i < NB; i += 256) hist[b * NB + i] = h[i];
}

// bucket totals (coalesced per iteration).
__global__ void k_btot(const int* __restrict__ hist, int* __restrict__ bcnt) {
    int t = blockIdx.x * 256 + threadIdx.x;
    if (t < NB) {
        int s = 0;
        for (int b = 0; b < SCB; b++) s += hist[b * NB + t];
        bcnt[t] = s;
    }
}

// exclusive scan of bcnt[NB] -> bstart (single block, 256 thr x 7 items).
__global__ void k_bscan(const int* __restrict__ bcnt, int* __restrict__ bstart, int B, int E) {
    __shared__ int ts[256];
    int t = threadIdx.x;
    int loc[7];
    int s = 0;
    for (int i = 0; i < 7; i++) {
        int idx = t * 7 + i;
        loc[i] = (idx < B) ? bcnt[idx] : 0;
        s += loc[i];
    }
    ts[t] = s;
    __syncthreads();
    for (int off = 1; off < 256; off <<= 1) {
        int add = (t >= off) ? ts[t - off] : 0;
        __syncthreads();
        ts[t] += add;
        __syncthreads();
    }
    int ex = ts[t] - s;
    for (int i = 0; i < 7; i++) {
        int idx = t * 7 + i;
        if (idx < B) bstart[idx] = ex;
        ex += loc[i];
    }
    if (t == 0) bstart[B] = E;
}

// convert hist[block][bucket] into absolute write bases.
__global__ void k_hcol(int* __restrict__ hist, const int* __restrict__ bstart) {
    int t = blockIdx.x * 256 + threadIdx.x;
    if (t < NB) {
        int run = bstart[t];
        for (int b = 0; b < SCB; b++) {
            int idx = b * NB + t;
            int v = hist[idx];
            hist[idx] = run;
            run += v;
        }
    }
}

// scatter edges into exclusive per-(block,bucket) regions via LDS cursors.
__global__ void k_scatter(const int* __restrict__ row, const int* __restrict__ col,
                          const int* __restrict__ hist, u32* __restrict__ ebuf, int E) {
    __shared__ int cur[NB];
    int b = blockIdx.x;
    for (int i = threadIdx.x; i < NB; i += 256) cur[i] = hist[b * NB + i];
    __syncthreads();
    int s = b * EPB, e = min(s + EPB, E);
    for (int i = s + threadIdx.x; i < e; i += 256) {
        int c = col[i];
        int p = atomicAdd(&cur[c >> 6], 1);
        ebuf[p] = ((u32)row[i] << 6) | (u32)(c & 63);  // row<2^17: fits 23 bits
    }
}

// dinv from bucketized edges: LDS counts, sequential writes, no global atomics.
__global__ void k_degb(const u32* __restrict__ ebuf, const int* __restrict__ bstart,
                       float* __restrict__ dinv, int N) {
    __shared__ int lcnt[64];
    int b = blockIdx.x, t = threadIdx.x;
    if (t < 64) lcnt[t] = 0;
    __syncthreads();
    int s = bstart[b], e = bstart[b + 1];
    for (int i = s + t; i < e; i += 256) {
        atomicAdd(&lcnt[ebuf[i] & 63u], 1);
    }
    __syncthreads();
    if (t < 64) {
        int node = b * 64 + t;
        if (node < N) dinv[node] = rsqrtf((float)(lcnt[t] + 1));  // +1 self-loop
    }
}

// ---------------- dense compute ----------------

// m'[node,64] = bf16( (in[node,:]@W) * dinv[node] ).  float4-staged input.
// If bnStats != nullptr, the staged input is relu(BN(in)) instead of raw in.
template<int K>
__global__ void k_gemm(const float* __restrict__ h, const float* __restrict__ W,
                       const float* __restrict__ dinv, u16* __restrict__ m, int N,
                       const float* __restrict__ bnStats, const float* __restrict__ bnG,
                       const float* __restrict__ bnB) {
    __shared__ float sh[16][K];
    const float invN = 1.0f / (float)N;
    const int K4 = K / 4;                 // float4s per row
    int block0 = blockIdx.x * 16;
    for (int idx = threadIdx.x; idx < 16 * K4; idx += 256) {
        int nn = idx / K4, kk4 = idx % K4;
        int node = block0 + nn;
        float4 v = make_float4(0.f, 0.f, 0.f, 0.f);
        if (node < N) v = *(const float4*)(h + (size_t)node * K + kk4 * 4);
        if (bnStats) {
            #pragma unroll
            for (int j = 0; j < 4; j++) {
                int kk = kk4 * 4 + j;
                float mean = bnStats[kk] * invN;
                float var = bnStats[K + kk] * invN - mean * mean;
                float sc = bnG[kk] * rsqrtf(var + BN_EPS);
                float* pv = (j == 0) ? &v.x : (j == 1) ? &v.y : (j == 2) ? &v.z : &v.w;
                *pv = fmaxf((*pv - mean) * sc + bnB[kk], 0.f);
            }
        }
        *(float4*)(&sh[nn][kk4 * 4]) = v;
    }
    __syncthreads();
    int colj = threadIdx.x & 63;
    int nl = threadIdx.x >> 6;  // 0..3 (uniform per wave -> LDS broadcast reads)
    float a0 = 0.f, a1 = 0.f, a2 = 0.f, a3 = 0.f;
    #pragma unroll 8
    for (int k = 0; k < K; k++) {
        float w = W[k * HID + colj];  // L1-resident (<=32KB)
        a0 += sh[nl][k] * w;
        a1 += sh[nl + 4][k] * w;
        a2 += sh[nl + 8][k] * w;
        a3 += sh[nl + 12][k] * w;
    }
    int n0 = block0 + nl;
    if (n0 < N)      m[(size_t)n0 * HID + colj]        = f2bf(a0 * dinv[n0]);
    if (n0 + 4 < N)  m[(size_t)(n0 + 4) * HID + colj]  = f2bf(a1 * dinv[n0 + 4]);
    if (n0 + 8 < N)  m[(size_t)(n0 + 8) * HID + colj]  = f2bf(a2 * dinv[n0 + 8]);
    if (n0 + 12 < N) m[(size_t)(n0 + 12) * HID + colj] = f2bf(a3 * dinv[n0 + 12]);
}

// gemm3 staging computes h2 = relu( BN2(agg2) + relu(BN1(agg1)) ) on the fly.
__global__ void k_gemm3(const float* __restrict__ agg1, const float* __restrict__ agg2,
                        const float* __restrict__ st1, const float* __restrict__ st2,
                        const float* __restrict__ g1, const float* __restrict__ be1,
                        const float* __restrict__ g2, const float* __restrict__ be2,
                        const float* __restrict__ W, const float* __restrict__ dinv,
                        u16* __restrict__ m, int N) {
    __shared__ float sh[16][HID];
    const float invN = 1.0f / (float)N;
    int block0 = blockIdx.x * 16;
    for (int idx = threadIdx.x; idx < 16 * 16; idx += 256) {   // 16 float4 per row
        int nn = idx / 16, kk4 = idx % 16;
        int node = block0 + nn;
        float4 o = make_float4(0.f, 0.f, 0.f, 0.f);
        if (node < N) {
            size_t p = (size_t)node * HID + kk4 * 4;
            float4 v1 = *(const float4*)(agg1 + p);
            float4 v2 = *(const float4*)(agg2 + p);
            float* p1 = &v1.x; float* p2 = &v2.x; float* po = &o.x;
            #pragma unroll
            for (int j = 0; j < 4; j++) {
                int kk = kk4 * 4 + j;
                float m1 = st1[kk] * invN;
                float va1 = st1[64 + kk] * invN - m1 * m1;
                float s1 = g1[kk] * rsqrtf(va1 + BN_EPS);
                float h1 = fmaxf((p1[j] - m1) * s1 + be1[kk], 0.f);
                float m2 = st2[kk] * invN;
                float va2 = st2[64 + kk] * invN - m2 * m2;
                float s2 = g2[kk] * rsqrtf(va2 + BN_EPS);
                po[j] = fmaxf((p2[j] - m2) * s2 + be2[kk] + h1, 0.f);
            }
        }
        *(float4*)(&sh[nn][kk4 * 4]) = o;
    }
    __syncthreads();
    int colj = threadIdx.x & 63;
    int nl = threadIdx.x >> 6;
    float a0 = 0.f, a1 = 0.f, a2 = 0.f, a3 = 0.f;
    #pragma unroll 8
    for (int k = 0; k < HID; k++) {
        float w = W[k * HID + colj];
        a0 += sh[nl][k] * w;
        a1 += sh[nl + 4][k] * w;
        a2 += sh[nl + 8][k] * w;
        a3 += sh[nl + 12][k] * w;
    }
    int n0 = block0 + nl;
    if (n0 < N)      m[(size_t)n0 * HID + colj]        = f2bf(a0 * dinv[n0]);
    if (n0 + 4 < N)  m[(size_t)(n0 + 4) * HID + colj]  = f2bf(a1 * dinv[n0 + 4]);
    if (n0 + 8 < N)  m[(size_t)(n0 + 8) * HID + colj]  = f2bf(a2 * dinv[n0 + 8]);
    if (n0 + 12 < N) m[(size_t)(n0 + 12) * HID + colj] = f2bf(a3 * dinv[n0 + 12]);
}

// fused aggregation v5: edge-parallel LDS-atomic tile.  One block per 64-node
// bucket; 32 groups x 8 lanes stream edges with NO loop-carried deps: group
// reads ebuf[i] (broadcast), gathers its 16B row slice, ds_add_f32 into
// tile[col].  Self-loop + dinv scale + BN stats in epilogue.
__global__ void __launch_bounds__(256)
k_fusedagg(const u16* __restrict__ m, const float* __restrict__ dinv,
           const u32* __restrict__ ebuf, const int* __restrict__ bstart,
           float* __restrict__ agg, float* __restrict__ stats, int N) {
    __shared__ float tile[64][64];
    __shared__ float rs[4][64], rq[4][64];
    int b = blockIdx.x, t = threadIdx.x;
    int lane = t & 63, w = t >> 6;
    // zero tile (float4-wide)
    for (int i = t; i < 64 * 64 / 4; i += 256)
        ((float4*)tile)[i] = make_float4(0.f, 0.f, 0.f, 0.f);
    __syncthreads();
    int s = bstart[b], e = bstart[b + 1];
    int sub = t & 7;        // 16B slice of the row (features sub*8..sub*8+7)
    #pragma unroll 2
    for (int i = s + (t >> 3); i < e; i += 32) {
        u32 v = ebuf[i];                       // broadcast across the 8 lanes
        int c = (int)(v & 63u);
        int r = (int)(v >> 6);
        uint4 u = ((const uint4*)(m + ((size_t)r << 6)))[sub];
        float* tc = &tile[c][sub * 8];
        atomicAdd(&tc[0], bf2f(u.x & 0xffffu));
        atomicAdd(&tc[1], bf2f(u.x >> 16));
        atomicAdd(&tc[2], bf2f(u.y & 0xffffu));
        atomicAdd(&tc[3], bf2f(u.y >> 16));
        atomicAdd(&tc[4], bf2f(u.z & 0xffffu));
        atomicAdd(&tc[5], bf2f(u.z >> 16));
        atomicAdd(&tc[6], bf2f(u.w & 0xffffu));
        atomicAdd(&tc[7], bf2f(u.w >> 16));
    }
    __syncthreads();
    // epilogue: each wave owns 16 nodes; lane = feature.
    int node0 = b * 64;
    float sum = 0.f, sq = 0.f;
    #pragma unroll 4
    for (int i = 0; i < 16; i++) {
        int c = w * 16 + i;
        int node = node0 + c;
        if (node < N) {
            float acc = bf2f((u32)m[(size_t)node * HID + lane]) + tile[c][lane];
            float val = acc * dinv[node];
            agg[(size_t)node * HID + lane] = val;
            sum += val; sq += val * val;
        }
    }
    rs[w][lane] = sum; rq[w][lane] = sq;
    __syncthreads();
    if (w == 0) {
        float a = rs[0][lane] + rs[1][lane] + rs[2][lane] + rs[3][lane];
        float q = rq[0][lane] + rq[1][lane] + rq[2][lane] + rq[3][lane];
        atomicAdd(&stats[lane], a);
        atomicAdd(&stats[64 + lane], q);
    }
}

// sorted-batch run-length pooling with BN3+relu applied inline.
__global__ void k_pool(const float* __restrict__ agg3, const float* __restrict__ st3,
                       const float* __restrict__ g3, const float* __restrict__ be3,
                       const int* __restrict__ batch, float* __restrict__ pooled,
                       float* __restrict__ gcnt, int N) {
    int lane = threadIdx.x;  // blockDim = 64
    int start = blockIdx.x * 64;
    if (start >= N) return;
    const float invN = 1.0f / (float)N;
    float mean = st3[lane] * invN;
    float var = st3[64 + lane] * invN - mean * mean;
    float sc = g3[lane] * rsqrtf(var + BN_EPS);
    float bb = be3[lane];
    int end = min(start + 64, N);
    int gcur = batch[start];
    float acc = 0.f; int run = 0;
    for (int n = start; n < end; n++) {
        int g = batch[n];
        if (g != gcur) {
            atomicAdd(&pooled[gcur * HID + lane], acc);
            if (lane == 0) atomicAdd(&gcnt[gcur], (float)run);
            acc = 0.f; run = 0; gcur = g;
        }
        acc += fmaxf((agg3[(size_t)n * HID + lane] - mean) * sc + bb, 0.f);
        run++;
    }
    atomicAdd(&pooled[gcur * HID + lane], acc);
    if (lane == 0) atomicAdd(&gcnt[gcur], (float)run);
}

// out[g] = dot(pooled[g]/max(cnt,1), fcw) + fcb.  wave per graph.
__global__ void k_final(const float* __restrict__ pooled, const float* __restrict__ gcnt,
                        const float* __restrict__ fcw, const float* __restrict__ fcb,
                        float* __restrict__ out) {
    int g = (int)((blockIdx.x * (size_t)blockDim.x + threadIdx.x) >> 6);
    int lane = threadIdx.x & 63;
    if (g >= NG) return;
    float c = fmaxf(gcnt[g], 1.f);
    float v = pooled[g * HID + lane] / c * fcw[lane];
    for (int off = 32; off > 0; off >>= 1) v += __shfl_down(v, off, 64);
    if (lane == 0) out[g] = v + fcb[0];
}

// ---------------- launch ----------------

extern "C" void kernel_launch(void* const* d_in, const int* in_sizes, int n_in,
                              void* d_out, int out_size, void* d_ws, size_t ws_size,
                              hipStream_t stream) {
    const float* x    = (const float*)d_in[0];
    const int*   ei   = (const int*)d_in[1];
    const int*   batch= (const int*)d_in[2];
    const float* w1   = (const float*)d_in[3];
    const float* g1   = (const float*)d_in[5];
    const float* be1  = (const float*)d_in[6];
    const float* w2   = (const float*)d_in[7];
    const float* g2   = (const float*)d_in[9];
    const float* be2  = (const float*)d_in[10];
    const float* w3   = (const float*)d_in[11];
    const float* g3   = (const float*)d_in[13];
    const float* be3  = (const float*)d_in[14];
    const float* fcw  = (const float*)d_in[15];
    const float* fcb  = (const float*)d_in[16];
    float* out = (float*)d_out;

    const int N = NN, E = NE;
    const int* erow = ei;       // edge_index[0] = source
    const int* ecol = ei + E;   // edge_index[1] = target

    char* ws = (char*)d_ws;
    size_t off = 0;
    auto alloc = [&](size_t bytes) -> char* {
        char* p = ws + off;
        off = (off + bytes + 255) & ~(size_t)255;
        return p;
    };
    float* dinv   = (float*)alloc((size_t)N * 4);
    int*   hist   = (int*)alloc((size_t)SCB * NB * 4);   // per-block bucket bases
    int*   bcnt   = (int*)alloc((size_t)NB * 4);
    int*   bstart = (int*)alloc((size_t)(NB + 1) * 4);
    u32*   ebuf   = (u32*)alloc((size_t)E * 4);          // bucketized packed edges
    u16*   bufM   = (u16*)alloc((size_t)N * HID * 2);    // m' (bf16, dinv-scaled)
    float* aggB1  = (float*)alloc((size_t)N * HID * 4);  // agg1, reused as agg3
    float* aggB2  = (float*)alloc((size_t)N * HID * 4);  // agg2
    float* stats  = (float*)alloc(3 * 128 * 4);
    float* pooled = (float*)alloc((size_t)NG * HID * 4);
    float* gcnt   = (float*)alloc((size_t)NG * 4);
    (void)ws_size; (void)in_sizes; (void)n_in; (void)out_size;

    float* aggB3 = aggB1;  // agg1 last read in k_gemm3, before layer-3 agg

    hipMemsetAsync(stats, 0, 3 * 128 * 4, stream);
    hipMemsetAsync(pooled, 0, (size_t)NG * HID * 4, stream);
    hipMemsetAsync(gcnt, 0, (size_t)NG * 4, stream);

    const int nbNode16 = (N + 15) / 16;    // 6250
    const int nbB = (NB + 255) / 256;      // 7

    // graph build: multisplit with private regions
    k_hist<<<SCB, 256, 0, stream>>>(ecol, hist, E);
    k_btot<<<nbB, 256, 0, stream>>>(hist, bcnt);
    k_bscan<<<1, 256, 0, stream>>>(bcnt, bstart, NB, E);
    k_hcol<<<nbB, 256, 0, stream>>>(hist, bstart);
    k_scatter<<<SCB, 256, 0, stream>>>(erow, ecol, hist, ebuf, E);
    k_degb<<<NB, 256, 0, stream>>>(ebuf, bstart, dinv, N);

    // layer 1
    k_gemm<INDIM><<<nbNode16, 256, 0, stream>>>(x, w1, dinv, bufM, N,
                                                nullptr, nullptr, nullptr);
    k_fusedagg<<<NB, 256, 0, stream>>>(bufM, dinv, ebuf, bstart, aggB1, stats, N);

    // layer 2 (gemm stages relu(BN1(agg1)))
    k_gemm<HID><<<nbNode16, 256, 0, stream>>>(aggB1, w2, dinv, bufM, N,
                                              stats, g1, be1);
    k_fusedagg<<<NB, 256, 0, stream>>>(bufM, dinv, ebuf, bstart, aggB2, stats + 128, N);

    // layer 3 (gemm stages h2 = relu(BN2(agg2) + relu(BN1(agg1))))
    k_gemm3<<<nbNode16, 256, 0, stream>>>(aggB1, aggB2, stats, stats + 128,
                                          g1, be1, g2, be2, w3, dinv, bufM, N);
    k_fusedagg<<<NB, 256, 0, stream>>>(bufM, dinv, ebuf, bstart, aggB3, stats + 256, N);

    // pool (BN3+relu inline) + final
    k_pool<<<(N + 63) / 64, 64, 0, stream>>>(aggB3, stats + 256, g3, be3,
                                             batch, pooled, gcnt, N);
    k_final<<<(NG * 64) / 256, 256, 0, stream>>>(pooled, gcnt, fcw, fcb, out);
}

// Round 11
// 605.433 us; speedup vs baseline: 3.4040x; 3.4040x over previous
//
#include <hip/hip_runtime.h>

#define NN 100000
#define NE 1600000
#define INDIM 128
#define HID 64
#define NG 1024
#define NB 1563            // ceil(NN/64) buckets of 64 target nodes
#define SCB 256            // scatter blocks (private-region multisplit)
#define EPB ((NE + SCB - 1) / SCB)   // 6250 edges per scatter block
#define SEGCAP 2048        // max edges per bucket (avg 1024; generous margin)
#define BN_EPS 1e-5f

typedef unsigned short u16;
typedef unsigned int u32;

__device__ __forceinline__ u16 f2bf(float f) {
    u32 u = __float_as_uint(f);
    u32 r = (u + 0x7fffu + ((u >> 16) & 1u)) >> 16;   // RNE
    return (u16)r;
}
__device__ __forceinline__ float bf2f(u32 b) {
    return __uint_as_float(b << 16);
}

// ---------------- graph preprocessing ----------------

// per-block bucket histogram (LDS only).
__global__ void k_hist(const int* __restrict__ col, int* __restrict__ hist, int E) {
    __shared__ int h[NB];
    int b = blockIdx.x;
    for (int i = threadIdx.x; i < NB; i += 256) h[i] = 0;
    __syncthreads();
    int s = b * EPB, e = min(s + EPB, E);
    for (int i = s + threadIdx.x; i < e; i += 256) {
        atomicAdd(&h[col[i] >> 6], 1);
    }
    __syncthreads();
    for (int i = threadIdx.x; i < NB; i += 256) hist[b * NB + i] = h[i];
}

// bucket totals (coalesced per iteration).
__global__ void k_btot(const int* __restrict__ hist, int* __restrict__ bcnt) {
    int t = blockIdx.x * 256 + threadIdx.x;
    if (t < NB) {
        int s = 0;
        for (int b = 0; b < SCB; b++) s += hist[b * NB + t];
        bcnt[t] = s;
    }
}

// exclusive scan of bcnt[NB] -> bstart (single block, 256 thr x 7 items).
__global__ void k_bscan(const int* __restrict__ bcnt, int* __restrict__ bstart, int B, int E) {
    __shared__ int ts[256];
    int t = threadIdx.x;
    int loc[7];
    int s = 0;
    for (int i = 0; i < 7; i++) {
        int idx = t * 7 + i;
        loc[i] = (idx < B) ? bcnt[idx] : 0;
        s += loc[i];
    }
    ts[t] = s;
    __syncthreads();
    for (int off = 1; off < 256; off <<= 1) {
        int add = (t >= off) ? ts[t - off] : 0;
        __syncthreads();
        ts[t] += add;
        __syncthreads();
    }
    int ex = ts[t] - s;
    for (int i = 0; i < 7; i++) {
        int idx = t * 7 + i;
        if (idx < B) bstart[idx] = ex;
        ex += loc[i];
    }
    if (t == 0) bstart[B] = E;
}

// convert hist[block][bucket] into absolute write bases.
__global__ void k_hcol(int* __restrict__ hist, const int* __restrict__ bstart) {
    int t = blockIdx.x * 256 + threadIdx.x;
    if (t < NB) {
        int run = bstart[t];
        for (int b = 0; b < SCB; b++) {
            int idx = b * NB + t;
            int v = hist[idx];
            hist[idx] = run;
            run += v;
        }
    }
}

// scatter edges into exclusive per-(block,bucket) regions via LDS cursors.
__global__ void k_scatter(const int* __restrict__ row, const int* __restrict__ col,
                          const int* __restrict__ hist, u32* __restrict__ ebuf, int E) {
    __shared__ int cur[NB];
    int b = blockIdx.x;
    for (int i = threadIdx.x; i < NB; i += 256) cur[i] = hist[b * NB + i];
    __syncthreads();
    int s = b * EPB, e = min(s + EPB, E);
    for (int i = s + threadIdx.x; i < e; i += 256) {
        int c = col[i];
        int p = atomicAdd(&cur[c >> 6], 1);
        ebuf[p] = ((u32)row[i] << 6) | (u32)(c & 63);  // row<2^17: fits 23 bits
    }
}

// build the global CSR once: block per bucket, LDS counts+scan, write
// glrows (node-sorted source ids), goffs (global CSR offsets), and dinv.
__global__ void __launch_bounds__(256)
k_csr(const u32* __restrict__ ebuf, const int* __restrict__ bstart,
      u32* __restrict__ glrows, int* __restrict__ goffs,
      float* __restrict__ dinv, int N) {
    __shared__ u32 seg[SEGCAP];
    __shared__ int lcnt[64], lstart[64], lcur[64];
    int b = blockIdx.x, t = threadIdx.x;
    int lane = t & 63, w = t >> 6;
    int s = bstart[b];
    int cnt = min(bstart[b + 1] - s, SEGCAP);
    if (t < 64) { lcnt[t] = 0; lcur[t] = 0; }
    __syncthreads();
    for (int i = t; i < cnt; i += 256) {
        u32 v = ebuf[s + i];
        seg[i] = v;
        atomicAdd(&lcnt[v & 63u], 1);
    }
    __syncthreads();
    if (w == 0) {  // wave-wide exclusive scan of 64 counts
        int v = lcnt[lane];
        int x = v;
        for (int o = 1; o < 64; o <<= 1) {
            int y = __shfl_up(x, o, 64);
            if (lane >= o) x += y;
        }
        lstart[lane] = x - v;
    }
    __syncthreads();
    for (int i = t; i < cnt; i += 256) {
        u32 v = seg[i];
        int c = (int)(v & 63u);
        int p = s + lstart[c] + atomicAdd(&lcur[c], 1);
        glrows[p] = v >> 6;
    }
    if (t < 64) {
        int node = b * 64 + t;
        if (node < N) {
            goffs[node] = s + lstart[t];
            dinv[node] = rsqrtf((float)(lcnt[t] + 1));  // +1 self-loop
        } else if (node == N) {
            goffs[N] = s + lstart[t];  // == E (all locals below this lane)
        }
    }
}

// ---------------- dense compute ----------------

// m'[node,64] = bf16( (in[node,:]@W) * dinv[node] ).  float4-staged input.
// If bnStats != nullptr, the staged input is relu(BN(in)) instead of raw in.
template<int K>
__global__ void k_gemm(const float* __restrict__ h, const float* __restrict__ W,
                       const float* __restrict__ dinv, u16* __restrict__ m, int N,
                       const float* __restrict__ bnStats, const float* __restrict__ bnG,
                       const float* __restrict__ bnB) {
    __shared__ float sh[16][K];
    const float invN = 1.0f / (float)N;
    const int K4 = K / 4;                 // float4s per row
    int block0 = blockIdx.x * 16;
    for (int idx = threadIdx.x; idx < 16 * K4; idx += 256) {
        int nn = idx / K4, kk4 = idx % K4;
        int node = block0 + nn;
        float4 v = make_float4(0.f, 0.f, 0.f, 0.f);
        if (node < N) v = *(const float4*)(h + (size_t)node * K + kk4 * 4);
        if (bnStats) {
            #pragma unroll
            for (int j = 0; j < 4; j++) {
                int kk = kk4 * 4 + j;
                float mean = bnStats[kk] * invN;
                float var = bnStats[K + kk] * invN - mean * mean;
                float sc = bnG[kk] * rsqrtf(var + BN_EPS);
                float* pv = (j == 0) ? &v.x : (j == 1) ? &v.y : (j == 2) ? &v.z : &v.w;
                *pv = fmaxf((*pv - mean) * sc + bnB[kk], 0.f);
            }
        }
        *(float4*)(&sh[nn][kk4 * 4]) = v;
    }
    __syncthreads();
    int colj = threadIdx.x & 63;
    int nl = threadIdx.x >> 6;  // 0..3 (uniform per wave -> LDS broadcast reads)
    float a0 = 0.f, a1 = 0.f, a2 = 0.f, a3 = 0.f;
    #pragma unroll 8
    for (int k = 0; k < K; k++) {
        float w = W[k * HID + colj];  // L1-resident (<=32KB)
        a0 += sh[nl][k] * w;
        a1 += sh[nl + 4][k] * w;
        a2 += sh[nl + 8][k] * w;
        a3 += sh[nl + 12][k] * w;
    }
    int n0 = block0 + nl;
    if (n0 < N)      m[(size_t)n0 * HID + colj]        = f2bf(a0 * dinv[n0]);
    if (n0 + 4 < N)  m[(size_t)(n0 + 4) * HID + colj]  = f2bf(a1 * dinv[n0 + 4]);
    if (n0 + 8 < N)  m[(size_t)(n0 + 8) * HID + colj]  = f2bf(a2 * dinv[n0 + 8]);
    if (n0 + 12 < N) m[(size_t)(n0 + 12) * HID + colj] = f2bf(a3 * dinv[n0 + 12]);
}

// gemm3 staging computes h2 = relu( BN2(agg2) + relu(BN1(agg1)) ) on the fly.
__global__ void k_gemm3(const float* __restrict__ agg1, const float* __restrict__ agg2,
                        const float* __restrict__ st1, const float* __restrict__ st2,
                        const float* __restrict__ g1, const float* __restrict__ be1,
                        const float* __restrict__ g2, const float* __restrict__ be2,
                        const float* __restrict__ W, const float* __restrict__ dinv,
                        u16* __restrict__ m, int N) {
    __shared__ float sh[16][HID];
    const float invN = 1.0f / (float)N;
    int block0 = blockIdx.x * 16;
    for (int idx = threadIdx.x; idx < 16 * 16; idx += 256) {   // 16 float4 per row
        int nn = idx / 16, kk4 = idx % 16;
        int node = block0 + nn;
        float4 o = make_float4(0.f, 0.f, 0.f, 0.f);
        if (node < N) {
            size_t p = (size_t)node * HID + kk4 * 4;
            float4 v1 = *(const float4*)(agg1 + p);
            float4 v2 = *(const float4*)(agg2 + p);
            float* p1 = &v1.x; float* p2 = &v2.x; float* po = &o.x;
            #pragma unroll
            for (int j = 0; j < 4; j++) {
                int kk = kk4 * 4 + j;
                float m1 = st1[kk] * invN;
                float va1 = st1[64 + kk] * invN - m1 * m1;
                float s1 = g1[kk] * rsqrtf(va1 + BN_EPS);
                float h1 = fmaxf((p1[j] - m1) * s1 + be1[kk], 0.f);
                float m2 = st2[kk] * invN;
                float va2 = st2[64 + kk] * invN - m2 * m2;
                float s2 = g2[kk] * rsqrtf(va2 + BN_EPS);
                po[j] = fmaxf((p2[j] - m2) * s2 + be2[kk] + h1, 0.f);
            }
        }
        *(float4*)(&sh[nn][kk4 * 4]) = o;
    }
    __syncthreads();
    int colj = threadIdx.x & 63;
    int nl = threadIdx.x >> 6;
    float a0 = 0.f, a1 = 0.f, a2 = 0.f, a3 = 0.f;
    #pragma unroll 8
    for (int k = 0; k < HID; k++) {
        float w = W[k * HID + colj];
        a0 += sh[nl][k] * w;
        a1 += sh[nl + 4][k] * w;
        a2 += sh[nl + 8][k] * w;
        a3 += sh[nl + 12][k] * w;
    }
    int n0 = block0 + nl;
    if (n0 < N)      m[(size_t)n0 * HID + colj]        = f2bf(a0 * dinv[n0]);
    if (n0 + 4 < N)  m[(size_t)(n0 + 4) * HID + colj]  = f2bf(a1 * dinv[n0 + 4]);
    if (n0 + 8 < N)  m[(size_t)(n0 + 8) * HID + colj]  = f2bf(a2 * dinv[n0 + 8]);
    if (n0 + 12 < N) m[(size_t)(n0 + 12) * HID + colj] = f2bf(a3 * dinv[n0 + 12]);
}

// fused aggregation v6: global CSR + feature-split.  grid (NB, 2).
// Block (b,h): 64 nodes, feature half h (32 feats).  4 waves x 16 nodes;
// per node: 8 edge-groups x 8 lanes, uint2 (4 bf16 feats) per lane.
__global__ void __launch_bounds__(256)
k_fusedagg(const u16* __restrict__ m, const float* __restrict__ dinv,
           const u32* __restrict__ glrows, const int* __restrict__ goffs,
           float* __restrict__ agg, float* __restrict__ stats, int N) {
    __shared__ float rs[4][32], rq[4][32];
    int b = blockIdx.x, hh = blockIdx.y;
    int t = threadIdx.x;
    int lane = t & 63, w = t >> 6;
    int g = lane >> 3;       // edge group 0..7
    int sub = lane & 7;      // feature quad within the half
    int qidx = hh * 8 + sub; // uint2 index into the 64-feat row
    int node0 = b * 64;
    float ssum[4] = {0.f, 0.f, 0.f, 0.f}, ssq[4] = {0.f, 0.f, 0.f, 0.f};
    for (int i = 0; i < 16; i++) {
        int node = node0 + w * 16 + i;
        if (node >= N) continue;
        float a0 = 0.f, a1 = 0.f, a2 = 0.f, a3 = 0.f;
        if (g == 0) {  // self-loop message (group 0 only)
            uint2 v = ((const uint2*)(m + ((size_t)node << 6)))[qidx];
            a0 = bf2f(v.x & 0xffffu); a1 = bf2f(v.x >> 16);
            a2 = bf2f(v.y & 0xffffu); a3 = bf2f(v.y >> 16);
        }
        int s = goffs[node], e = goffs[node + 1];
        #pragma unroll 2
        for (int k = s + g; k < e; k += 8) {
            int r = (int)glrows[k];
            uint2 v = ((const uint2*)(m + ((size_t)r << 6)))[qidx];
            a0 += bf2f(v.x & 0xffffu); a1 += bf2f(v.x >> 16);
            a2 += bf2f(v.y & 0xffffu); a3 += bf2f(v.y >> 16);
        }
        // reduce across 8 edge groups (lanes sub, sub+8, ..., sub+56)
        a0 += __shfl_xor(a0, 8, 64); a0 += __shfl_xor(a0, 16, 64); a0 += __shfl_xor(a0, 32, 64);
        a1 += __shfl_xor(a1, 8, 64); a1 += __shfl_xor(a1, 16, 64); a1 += __shfl_xor(a1, 32, 64);
        a2 += __shfl_xor(a2, 8, 64); a2 += __shfl_xor(a2, 16, 64); a2 += __shfl_xor(a2, 32, 64);
        a3 += __shfl_xor(a3, 8, 64); a3 += __shfl_xor(a3, 16, 64); a3 += __shfl_xor(a3, 32, 64);
        if (lane < 8) {
            float di = dinv[node];
            float v0 = a0 * di, v1 = a1 * di, v2 = a2 * di, v3 = a3 * di;
            *(float4*)(agg + ((size_t)node << 6) + hh * 32 + sub * 4) =
                make_float4(v0, v1, v2, v3);
            ssum[0] += v0; ssum[1] += v1; ssum[2] += v2; ssum[3] += v3;
            ssq[0] += v0 * v0; ssq[1] += v1 * v1; ssq[2] += v2 * v2; ssq[3] += v3 * v3;
        }
    }
    if (lane < 8) {
        #pragma unroll
        for (int j = 0; j < 4; j++) {
            rs[w][sub * 4 + j] = ssum[j];
            rq[w][sub * 4 + j] = ssq[j];
        }
    }
    __syncthreads();
    if (w == 0 && lane < 32) {
        float a = rs[0][lane] + rs[1][lane] + rs[2][lane] + rs[3][lane];
        float q = rq[0][lane] + rq[1][lane] + rq[2][lane] + rq[3][lane];
        atomicAdd(&stats[hh * 32 + lane], a);
        atomicAdd(&stats[64 + hh * 32 + lane], q);
    }
}

// sorted-batch run-length pooling with BN3+relu applied inline.
__global__ void k_pool(const float* __restrict__ agg3, const float* __restrict__ st3,
                       const float* __restrict__ g3, const float* __restrict__ be3,
                       const int* __restrict__ batch, float* __restrict__ pooled,
                       float* __restrict__ gcnt, int N) {
    int lane = threadIdx.x;  // blockDim = 64
    int start = blockIdx.x * 64;
    if (start >= N) return;
    const float invN = 1.0f / (float)N;
    float mean = st3[lane] * invN;
    float var = st3[64 + lane] * invN - mean * mean;
    float sc = g3[lane] * rsqrtf(var + BN_EPS);
    float bb = be3[lane];
    int end = min(start + 64, N);
    int gcur = batch[start];
    float acc = 0.f; int run = 0;
    for (int n = start; n < end; n++) {
        int g = batch[n];
        if (g != gcur) {
            atomicAdd(&pooled[gcur * HID + lane], acc);
            if (lane == 0) atomicAdd(&gcnt[gcur], (float)run);
            acc = 0.f; run = 0; gcur = g;
        }
        acc += fmaxf((agg3[(size_t)n * HID + lane] - mean) * sc + bb, 0.f);
        run++;
    }
    atomicAdd(&pooled[gcur * HID + lane], acc);
    if (lane == 0) atomicAdd(&gcnt[gcur], (float)run);
}

// out[g] = dot(pooled[g]/max(cnt,1), fcw) + fcb.  wave per graph.
__global__ void k_final(const float* __restrict__ pooled, const float* __restrict__ gcnt,
                        const float* __restrict__ fcw, const float* __restrict__ fcb,
                        float* __restrict__ out) {
    int g = (int)((blockIdx.x * (size_t)blockDim.x + threadIdx.x) >> 6);
    int lane = threadIdx.x & 63;
    if (g >= NG) return;
    float c = fmaxf(gcnt[g], 1.f);
    float v = pooled[g * HID + lane] / c * fcw[lane];
    for (int off = 32; off > 0; off >>= 1) v += __shfl_down(v, off, 64);
    if (lane == 0) out[g] = v + fcb[0];
}

// ---------------- launch ----------------

extern "C" void kernel_launch(void* const* d_in, const int* in_sizes, int n_in,
                              void* d_out, int out_size, void* d_ws, size_t ws_size,
                              hipStream_t stream) {
    const float* x    = (const float*)d_in[0];
    const int*   ei   = (const int*)d_in[1];
    const int*   batch= (const int*)d_in[2];
    const float* w1   = (const float*)d_in[3];
    const float* g1   = (const float*)d_in[5];
    const float* be1  = (const float*)d_in[6];
    const float* w2   = (const float*)d_in[7];
    const float* g2   = (const float*)d_in[9];
    const float* be2  = (const float*)d_in[10];
    const float* w3   = (const float*)d_in[11];
    const float* g3   = (const float*)d_in[13];
    const float* be3  = (const float*)d_in[14];
    const float* fcw  = (const float*)d_in[15];
    const float* fcb  = (const float*)d_in[16];
    float* out = (float*)d_out;

    const int N = NN, E = NE;
    const int* erow = ei;       // edge_index[0] = source
    const int* ecol = ei + E;   // edge_index[1] = target

    char* ws = (char*)d_ws;
    size_t off = 0;
    auto alloc = [&](size_t bytes) -> char* {
        char* p = ws + off;
        off = (off + bytes + 255) & ~(size_t)255;
        return p;
    };
    float* dinv   = (float*)alloc((size_t)N * 4);
    int*   hist   = (int*)alloc((size_t)SCB * NB * 4);   // per-block bucket bases
    int*   bcnt   = (int*)alloc((size_t)NB * 4);
    int*   bstart = (int*)alloc((size_t)(NB + 1) * 4);
    u32*   ebuf   = (u32*)alloc((size_t)E * 4);          // bucketized packed edges
    u32*   glrows = (u32*)alloc((size_t)E * 4);          // global CSR source ids
    int*   goffs  = (int*)alloc((size_t)(N + 1) * 4);    // global CSR offsets
    u16*   bufM   = (u16*)alloc((size_t)N * HID * 2);    // m' (bf16, dinv-scaled)
    float* aggB1  = (float*)alloc((size_t)N * HID * 4);  // agg1, reused as agg3
    float* aggB2  = (float*)alloc((size_t)N * HID * 4);  // agg2
    float* stats  = (float*)alloc(3 * 128 * 4);
    float* pooled = (float*)alloc((size_t)NG * HID * 4);
    float* gcnt   = (float*)alloc((size_t)NG * 4);
    (void)ws_size; (void)in_sizes; (void)n_in; (void)out_size;

    float* aggB3 = aggB1;  // agg1 last read in k_gemm3, before layer-3 agg

    hipMemsetAsync(stats, 0, 3 * 128 * 4, stream);
    hipMemsetAsync(pooled, 0, (size_t)NG * HID * 4, stream);
    hipMemsetAsync(gcnt, 0, (size_t)NG * 4, stream);

    const int nbNode16 = (N + 15) / 16;    // 6250
    const int nbB = (NB + 255) / 256;      // 7
    dim3 aggGrid(NB, 2);

    // graph build: multisplit with private regions, then one global CSR
    k_hist<<<SCB, 256, 0, stream>>>(ecol, hist, E);
    k_btot<<<nbB, 256, 0, stream>>>(hist, bcnt);
    k_bscan<<<1, 256, 0, stream>>>(bcnt, bstart, NB, E);
    k_hcol<<<nbB, 256, 0, stream>>>(hist, bstart);
    k_scatter<<<SCB, 256, 0, stream>>>(erow, ecol, hist, ebuf, E);
    k_csr<<<NB, 256, 0, stream>>>(ebuf, bstart, glrows, goffs, dinv, N);

    // layer 1
    k_gemm<INDIM><<<nbNode16, 256, 0, stream>>>(x, w1, dinv, bufM, N,
                                                nullptr, nullptr, nullptr);
    k_fusedagg<<<aggGrid, 256, 0, stream>>>(bufM, dinv, glrows, goffs, aggB1, stats, N);

    // layer 2 (gemm stages relu(BN1(agg1)))
    k_gemm<HID><<<nbNode16, 256, 0, stream>>>(aggB1, w2, dinv, bufM, N,
                                              stats, g1, be1);
    k_fusedagg<<<aggGrid, 256, 0, stream>>>(bufM, dinv, glrows, goffs, aggB2, stats + 128, N);

    // layer 3 (gemm stages h2 = relu(BN2(agg2) + relu(BN1(agg1))))
    k_gemm3<<<nbNode16, 256, 0, stream>>>(aggB1, aggB2, stats, stats + 128,
                                          g1, be1, g2, be2, w3, dinv, bufM, N);
    k_fusedagg<<<aggGrid, 256, 0, stream>>>(bufM, dinv, glrows, goffs, aggB3, stats + 256, N);

    // pool (BN3+relu inline) + final
    k_pool<<<(N + 63) / 64, 64, 0, stream>>>(aggB3, stats + 256, g3, be3,
                                             batch, pooled, gcnt, N);
    k_final<<<(NG * 64) / 256, 256, 0, stream>>>(pooled, gcnt, fcw, fcb, out);
}

// Round 12
// 550.530 us; speedup vs baseline: 3.7435x; 1.0997x over previous
//
#include <hip/hip_runtime.h>

#define NN 100000
#define NE 1600000
#define INDIM 128
#define HID 64
#define NG 1024
#define NB 1563            // ceil(NN/64) buckets of 64 target nodes
#define SCB 256            // scatter blocks (private-region multisplit)
#define EPB ((NE + SCB - 1) / SCB)   // 6250 edges per scatter block
#define SEGCAP 2048        // max edges per bucket (avg 1024; generous margin)
#define BN_EPS 1e-5f

typedef unsigned short u16;
typedef unsigned int u32;

__device__ __forceinline__ u16 f2bf(float f) {
    u32 u = __float_as_uint(f);
    u32 r = (u + 0x7fffu + ((u >> 16) & 1u)) >> 16;   // RNE
    return (u16)r;
}
__device__ __forceinline__ float bf2f(u32 b) {
    return __uint_as_float(b << 16);
}

// ---------------- graph preprocessing ----------------

// per-block bucket histogram (LDS only).
__global__ void k_hist(const int* __restrict__ col, int* __restrict__ hist, int E) {
    __shared__ int h[NB];
    int b = blockIdx.x;
    for (int i = threadIdx.x; i < NB; i += 256) h[i] = 0;
    __syncthreads();
    int s = b * EPB, e = min(s + EPB, E);
    for (int i = s + threadIdx.x; i < e; i += 256) {
        atomicAdd(&h[col[i] >> 6], 1);
    }
    __syncthreads();
    for (int i = threadIdx.x; i < NB; i += 256) hist[b * NB + i] = h[i];
}

// bucket totals (coalesced per iteration).
__global__ void k_btot(const int* __restrict__ hist, int* __restrict__ bcnt) {
    int t = blockIdx.x * 256 + threadIdx.x;
    if (t < NB) {
        int s = 0;
        for (int b = 0; b < SCB; b++) s += hist[b * NB + t];
        bcnt[t] = s;
    }
}

// exclusive scan of bcnt[NB] -> bstart (single block, 256 thr x 7 items).
__global__ void k_bscan(const int* __restrict__ bcnt, int* __restrict__ bstart, int B, int E) {
    __shared__ int ts[256];
    int t = threadIdx.x;
    int loc[7];
    int s = 0;
    for (int i = 0; i < 7; i++) {
        int idx = t * 7 + i;
        loc[i] = (idx < B) ? bcnt[idx] : 0;
        s += loc[i];
    }
    ts[t] = s;
    __syncthreads();
    for (int off = 1; off < 256; off <<= 1) {
        int add = (t >= off) ? ts[t - off] : 0;
        __syncthreads();
        ts[t] += add;
        __syncthreads();
    }
    int ex = ts[t] - s;
    for (int i = 0; i < 7; i++) {
        int idx = t * 7 + i;
        if (idx < B) bstart[idx] = ex;
        ex += loc[i];
    }
    if (t == 0) bstart[B] = E;
}

// convert hist[block][bucket] into absolute write bases.
__global__ void k_hcol(int* __restrict__ hist, const int* __restrict__ bstart) {
    int t = blockIdx.x * 256 + threadIdx.x;
    if (t < NB) {
        int run = bstart[t];
        for (int b = 0; b < SCB; b++) {
            int idx = b * NB + t;
            int v = hist[idx];
            hist[idx] = run;
            run += v;
        }
    }
}

// scatter edges into exclusive per-(block,bucket) regions via LDS cursors.
__global__ void k_scatter(const int* __restrict__ row, const int* __restrict__ col,
                          const int* __restrict__ hist, u32* __restrict__ ebuf, int E) {
    __shared__ int cur[NB];
    int b = blockIdx.x;
    for (int i = threadIdx.x; i < NB; i += 256) cur[i] = hist[b * NB + i];
    __syncthreads();
    int s = b * EPB, e = min(s + EPB, E);
    for (int i = s + threadIdx.x; i < e; i += 256) {
        int c = col[i];
        int p = atomicAdd(&cur[c >> 6], 1);
        ebuf[p] = ((u32)row[i] << 6) | (u32)(c & 63);  // row<2^17: fits 23 bits
    }
}

// build the global CSR once: block per bucket, LDS counts+scan, write
// glrows (node-sorted source ids), goffs (global CSR offsets), and dinv.
__global__ void __launch_bounds__(256)
k_csr(const u32* __restrict__ ebuf, const int* __restrict__ bstart,
      u32* __restrict__ glrows, int* __restrict__ goffs,
      float* __restrict__ dinv, int N) {
    __shared__ u32 seg[SEGCAP];
    __shared__ int lcnt[64], lstart[64], lcur[64];
    int b = blockIdx.x, t = threadIdx.x;
    int lane = t & 63, w = t >> 6;
    int s = bstart[b];
    int cnt = min(bstart[b + 1] - s, SEGCAP);
    if (t < 64) { lcnt[t] = 0; lcur[t] = 0; }
    __syncthreads();
    for (int i = t; i < cnt; i += 256) {
        u32 v = ebuf[s + i];
        seg[i] = v;
        atomicAdd(&lcnt[v & 63u], 1);
    }
    __syncthreads();
    if (w == 0) {  // wave-wide exclusive scan of 64 counts
        int v = lcnt[lane];
        int x = v;
        for (int o = 1; o < 64; o <<= 1) {
            int y = __shfl_up(x, o, 64);
            if (lane >= o) x += y;
        }
        lstart[lane] = x - v;
    }
    __syncthreads();
    for (int i = t; i < cnt; i += 256) {
        u32 v = seg[i];
        int c = (int)(v & 63u);
        int p = s + lstart[c] + atomicAdd(&lcur[c], 1);
        glrows[p] = v >> 6;
    }
    if (t < 64) {
        int node = b * 64 + t;
        if (node < N) {
            goffs[node] = s + lstart[t];
            dinv[node] = rsqrtf((float)(lcnt[t] + 1));  // +1 self-loop
        } else if (node == N) {
            goffs[N] = s + lstart[t];  // == E
        }
    }
}

// ---------------- dense compute ----------------

// layer-1 GEMM: f32 input.  m'[node,64] = bf16( (x@W1) * dinv[node] ).
template<int K>
__global__ void k_gemm(const float* __restrict__ h, const float* __restrict__ W,
                       const float* __restrict__ dinv, u16* __restrict__ m, int N) {
    __shared__ float sh[16][K];
    const int K4 = K / 4;
    int block0 = blockIdx.x * 16;
    for (int idx = threadIdx.x; idx < 16 * K4; idx += 256) {
        int nn = idx / K4, kk4 = idx % K4;
        int node = block0 + nn;
        float4 v = make_float4(0.f, 0.f, 0.f, 0.f);
        if (node < N) v = *(const float4*)(h + (size_t)node * K + kk4 * 4);
        *(float4*)(&sh[nn][kk4 * 4]) = v;
    }
    __syncthreads();
    int colj = threadIdx.x & 63;
    int nl = threadIdx.x >> 6;
    float a0 = 0.f, a1 = 0.f, a2 = 0.f, a3 = 0.f;
    #pragma unroll 8
    for (int k = 0; k < K; k++) {
        float w = W[k * HID + colj];
        a0 += sh[nl][k] * w;
        a1 += sh[nl + 4][k] * w;
        a2 += sh[nl + 8][k] * w;
        a3 += sh[nl + 12][k] * w;
    }
    int n0 = block0 + nl;
    if (n0 < N)      m[(size_t)n0 * HID + colj]        = f2bf(a0 * dinv[n0]);
    if (n0 + 4 < N)  m[(size_t)(n0 + 4) * HID + colj]  = f2bf(a1 * dinv[n0 + 4]);
    if (n0 + 8 < N)  m[(size_t)(n0 + 8) * HID + colj]  = f2bf(a2 * dinv[n0 + 8]);
    if (n0 + 12 < N) m[(size_t)(n0 + 12) * HID + colj] = f2bf(a3 * dinv[n0 + 12]);
}

// layer-2 GEMM: bf16 agg1 input; stages relu(BN1(agg1)).
__global__ void k_gemm2(const u16* __restrict__ h, const float* __restrict__ W,
                        const float* __restrict__ dinv, u16* __restrict__ m, int N,
                        const float* __restrict__ st, const float* __restrict__ bnG,
                        const float* __restrict__ bnB) {
    __shared__ float sh[16][HID];
    const float invN = 1.0f / (float)N;
    int block0 = blockIdx.x * 16;
    for (int idx = threadIdx.x; idx < 16 * 8; idx += 256) {   // 8 uint4 per row
        int nn = idx >> 3, k8 = idx & 7;
        int node = block0 + nn;
        float vals[8] = {0.f, 0.f, 0.f, 0.f, 0.f, 0.f, 0.f, 0.f};
        if (node < N) {
            uint4 v = ((const uint4*)(h + ((size_t)node << 6)))[k8];
            vals[0] = bf2f(v.x & 0xffffu); vals[1] = bf2f(v.x >> 16);
            vals[2] = bf2f(v.y & 0xffffu); vals[3] = bf2f(v.y >> 16);
            vals[4] = bf2f(v.z & 0xffffu); vals[5] = bf2f(v.z >> 16);
            vals[6] = bf2f(v.w & 0xffffu); vals[7] = bf2f(v.w >> 16);
            #pragma unroll
            for (int j = 0; j < 8; j++) {
                int kk = k8 * 8 + j;
                float mean = st[kk] * invN;
                float var = st[64 + kk] * invN - mean * mean;
                float sc = bnG[kk] * rsqrtf(var + BN_EPS);
                vals[j] = fmaxf((vals[j] - mean) * sc + bnB[kk], 0.f);
            }
        }
        *(float4*)(&sh[nn][k8 * 8])     = make_float4(vals[0], vals[1], vals[2], vals[3]);
        *(float4*)(&sh[nn][k8 * 8 + 4]) = make_float4(vals[4], vals[5], vals[6], vals[7]);
    }
    __syncthreads();
    int colj = threadIdx.x & 63;
    int nl = threadIdx.x >> 6;
    float a0 = 0.f, a1 = 0.f, a2 = 0.f, a3 = 0.f;
    #pragma unroll 8
    for (int k = 0; k < HID; k++) {
        float w = W[k * HID + colj];
        a0 += sh[nl][k] * w;
        a1 += sh[nl + 4][k] * w;
        a2 += sh[nl + 8][k] * w;
        a3 += sh[nl + 12][k] * w;
    }
    int n0 = block0 + nl;
    if (n0 < N)      m[(size_t)n0 * HID + colj]        = f2bf(a0 * dinv[n0]);
    if (n0 + 4 < N)  m[(size_t)(n0 + 4) * HID + colj]  = f2bf(a1 * dinv[n0 + 4]);
    if (n0 + 8 < N)  m[(size_t)(n0 + 8) * HID + colj]  = f2bf(a2 * dinv[n0 + 8]);
    if (n0 + 12 < N) m[(size_t)(n0 + 12) * HID + colj] = f2bf(a3 * dinv[n0 + 12]);
}

// layer-3 GEMM: bf16 agg1+agg2; stages h2 = relu(BN2(agg2) + relu(BN1(agg1))).
__global__ void k_gemm3(const u16* __restrict__ agg1, const u16* __restrict__ agg2,
                        const float* __restrict__ st1, const float* __restrict__ st2,
                        const float* __restrict__ g1, const float* __restrict__ be1,
                        const float* __restrict__ g2, const float* __restrict__ be2,
                        const float* __restrict__ W, const float* __restrict__ dinv,
                        u16* __restrict__ m, int N) {
    __shared__ float sh[16][HID];
    const float invN = 1.0f / (float)N;
    int block0 = blockIdx.x * 16;
    for (int idx = threadIdx.x; idx < 16 * 8; idx += 256) {
        int nn = idx >> 3, k8 = idx & 7;
        int node = block0 + nn;
        float o[8] = {0.f, 0.f, 0.f, 0.f, 0.f, 0.f, 0.f, 0.f};
        if (node < N) {
            uint4 v1 = ((const uint4*)(agg1 + ((size_t)node << 6)))[k8];
            uint4 v2 = ((const uint4*)(agg2 + ((size_t)node << 6)))[k8];
            float a1v[8], a2v[8];
            a1v[0] = bf2f(v1.x & 0xffffu); a1v[1] = bf2f(v1.x >> 16);
            a1v[2] = bf2f(v1.y & 0xffffu); a1v[3] = bf2f(v1.y >> 16);
            a1v[4] = bf2f(v1.z & 0xffffu); a1v[5] = bf2f(v1.z >> 16);
            a1v[6] = bf2f(v1.w & 0xffffu); a1v[7] = bf2f(v1.w >> 16);
            a2v[0] = bf2f(v2.x & 0xffffu); a2v[1] = bf2f(v2.x >> 16);
            a2v[2] = bf2f(v2.y & 0xffffu); a2v[3] = bf2f(v2.y >> 16);
            a2v[4] = bf2f(v2.z & 0xffffu); a2v[5] = bf2f(v2.z >> 16);
            a2v[6] = bf2f(v2.w & 0xffffu); a2v[7] = bf2f(v2.w >> 16);
            #pragma unroll
            for (int j = 0; j < 8; j++) {
                int kk = k8 * 8 + j;
                float m1 = st1[kk] * invN;
                float va1 = st1[64 + kk] * invN - m1 * m1;
                float s1 = g1[kk] * rsqrtf(va1 + BN_EPS);
                float h1 = fmaxf((a1v[j] - m1) * s1 + be1[kk], 0.f);
                float m2 = st2[kk] * invN;
                float va2 = st2[64 + kk] * invN - m2 * m2;
                float s2 = g2[kk] * rsqrtf(va2 + BN_EPS);
                o[j] = fmaxf((a2v[j] - m2) * s2 + be2[kk] + h1, 0.f);
            }
        }
        *(float4*)(&sh[nn][k8 * 8])     = make_float4(o[0], o[1], o[2], o[3]);
        *(float4*)(&sh[nn][k8 * 8 + 4]) = make_float4(o[4], o[5], o[6], o[7]);
    }
    __syncthreads();
    int colj = threadIdx.x & 63;
    int nl = threadIdx.x >> 6;
    float a0 = 0.f, a1 = 0.f, a2 = 0.f, a3 = 0.f;
    #pragma unroll 8
    for (int k = 0; k < HID; k++) {
        float w = W[k * HID + colj];
        a0 += sh[nl][k] * w;
        a1 += sh[nl + 4][k] * w;
        a2 += sh[nl + 8][k] * w;
        a3 += sh[nl + 12][k] * w;
    }
    int n0 = block0 + nl;
    if (n0 < N)      m[(size_t)n0 * HID + colj]        = f2bf(a0 * dinv[n0]);
    if (n0 + 4 < N)  m[(size_t)(n0 + 4) * HID + colj]  = f2bf(a1 * dinv[n0 + 4]);
    if (n0 + 8 < N)  m[(size_t)(n0 + 8) * HID + colj]  = f2bf(a2 * dinv[n0 + 8]);
    if (n0 + 12 < N) m[(size_t)(n0 + 12) * HID + colj] = f2bf(a3 * dinv[n0 + 12]);
}

// fused aggregation v7: global CSR, full rows, bf16 output.
// Block = 64-node bucket; 4 waves x 16 nodes; per node 4 edge-groups x 16
// lanes, uint2 (4 bf16 feats)/lane.  Stats computed in f32 pre-rounding.
__global__ void __launch_bounds__(256)
k_agg(const u16* __restrict__ m, const float* __restrict__ dinv,
      const u32* __restrict__ glrows, const int* __restrict__ goffs,
      u16* __restrict__ agg, float* __restrict__ stats, int N) {
    __shared__ float rs[4][64], rq[4][64];
    int t = threadIdx.x;
    int lane = t & 63, w = t >> 6;
    int g = lane >> 4;       // edge group 0..3
    int sub = lane & 15;     // uint2 feature quad
    int node0 = blockIdx.x * 64;
    float ssum[4] = {0.f, 0.f, 0.f, 0.f}, ssq[4] = {0.f, 0.f, 0.f, 0.f};
    for (int i = 0; i < 16; i++) {
        int node = node0 + w * 16 + i;
        if (node >= N) continue;
        float a0 = 0.f, a1 = 0.f, a2 = 0.f, a3 = 0.f;
        if (g == 0) {  // self-loop message (group 0 only)
            uint2 v = ((const uint2*)(m + ((size_t)node << 6)))[sub];
            a0 = bf2f(v.x & 0xffffu); a1 = bf2f(v.x >> 16);
            a2 = bf2f(v.y & 0xffffu); a3 = bf2f(v.y >> 16);
        }
        int s = goffs[node], e = goffs[node + 1];
        #pragma unroll 2
        for (int k = s + g; k < e; k += 4) {
            int r = (int)glrows[k];
            uint2 v = ((const uint2*)(m + ((size_t)r << 6)))[sub];
            a0 += bf2f(v.x & 0xffffu); a1 += bf2f(v.x >> 16);
            a2 += bf2f(v.y & 0xffffu); a3 += bf2f(v.y >> 16);
        }
        // reduce across the 4 edge groups (lanes sub, sub+16, sub+32, sub+48)
        a0 += __shfl_xor(a0, 16, 64); a0 += __shfl_xor(a0, 32, 64);
        a1 += __shfl_xor(a1, 16, 64); a1 += __shfl_xor(a1, 32, 64);
        a2 += __shfl_xor(a2, 16, 64); a2 += __shfl_xor(a2, 32, 64);
        a3 += __shfl_xor(a3, 16, 64); a3 += __shfl_xor(a3, 32, 64);
        if (lane < 16) {
            float di = dinv[node];
            float v0 = a0 * di, v1 = a1 * di, v2 = a2 * di, v3 = a3 * di;
            u32 lo = (u32)f2bf(v0) | ((u32)f2bf(v1) << 16);
            u32 hi = (u32)f2bf(v2) | ((u32)f2bf(v3) << 16);
            ((uint2*)(agg + ((size_t)node << 6)))[sub] = make_uint2(lo, hi);
            ssum[0] += v0; ssum[1] += v1; ssum[2] += v2; ssum[3] += v3;
            ssq[0] += v0 * v0; ssq[1] += v1 * v1; ssq[2] += v2 * v2; ssq[3] += v3 * v3;
        }
    }
    if (lane < 16) {
        #pragma unroll
        for (int j = 0; j < 4; j++) {
            rs[w][sub * 4 + j] = ssum[j];
            rq[w][sub * 4 + j] = ssq[j];
        }
    }
    __syncthreads();
    if (w == 0) {
        float a = rs[0][lane] + rs[1][lane] + rs[2][lane] + rs[3][lane];
        float q = rq[0][lane] + rq[1][lane] + rq[2][lane] + rq[3][lane];
        atomicAdd(&stats[lane], a);
        atomicAdd(&stats[64 + lane], q);
    }
}

// sorted-batch run-length pooling with BN3+relu applied inline (bf16 agg3).
__global__ void k_pool(const u16* __restrict__ agg3, const float* __restrict__ st3,
                       const float* __restrict__ g3, const float* __restrict__ be3,
                       const int* __restrict__ batch, float* __restrict__ pooled,
                       float* __restrict__ gcnt, int N) {
    int lane = threadIdx.x;  // blockDim = 64
    int start = blockIdx.x * 64;
    if (start >= N) return;
    const float invN = 1.0f / (float)N;
    float mean = st3[lane] * invN;
    float var = st3[64 + lane] * invN - mean * mean;
    float sc = g3[lane] * rsqrtf(var + BN_EPS);
    float bb = be3[lane];
    int end = min(start + 64, N);
    int gcur = batch[start];
    float acc = 0.f; int run = 0;
    for (int n = start; n < end; n++) {
        int g = batch[n];
        if (g != gcur) {
            atomicAdd(&pooled[gcur * HID + lane], acc);
            if (lane == 0) atomicAdd(&gcnt[gcur], (float)run);
            acc = 0.f; run = 0; gcur = g;
        }
        float v = bf2f((u32)agg3[(size_t)n * HID + lane]);
        acc += fmaxf((v - mean) * sc + bb, 0.f);
        run++;
    }
    atomicAdd(&pooled[gcur * HID + lane], acc);
    if (lane == 0) atomicAdd(&gcnt[gcur], (float)run);
}

// out[g] = dot(pooled[g]/max(cnt,1), fcw) + fcb.  wave per graph.
__global__ void k_final(const float* __restrict__ pooled, const float* __restrict__ gcnt,
                        const float* __restrict__ fcw, const float* __restrict__ fcb,
                        float* __restrict__ out) {
    int g = (int)((blockIdx.x * (size_t)blockDim.x + threadIdx.x) >> 6);
    int lane = threadIdx.x & 63;
    if (g >= NG) return;
    float c = fmaxf(gcnt[g], 1.f);
    float v = pooled[g * HID + lane] / c * fcw[lane];
    for (int off = 32; off > 0; off >>= 1) v += __shfl_down(v, off, 64);
    if (lane == 0) out[g] = v + fcb[0];
}

// ---------------- launch ----------------

extern "C" void kernel_launch(void* const* d_in, const int* in_sizes, int n_in,
                              void* d_out, int out_size, void* d_ws, size_t ws_size,
                              hipStream_t stream) {
    const float* x    = (const float*)d_in[0];
    const int*   ei   = (const int*)d_in[1];
    const int*   batch= (const int*)d_in[2];
    const float* w1   = (const float*)d_in[3];
    const float* g1   = (const float*)d_in[5];
    const float* be1  = (const float*)d_in[6];
    const float* w2   = (const float*)d_in[7];
    const float* g2   = (const float*)d_in[9];
    const float* be2  = (const float*)d_in[10];
    const float* w3   = (const float*)d_in[11];
    const float* g3   = (const float*)d_in[13];
    const float* be3  = (const float*)d_in[14];
    const float* fcw  = (const float*)d_in[15];
    const float* fcb  = (const float*)d_in[16];
    float* out = (float*)d_out;

    const int N = NN, E = NE;
    const int* erow = ei;       // edge_index[0] = source
    const int* ecol = ei + E;   // edge_index[1] = target

    char* ws = (char*)d_ws;
    size_t off = 0;
    auto alloc = [&](size_t bytes) -> char* {
        char* p = ws + off;
        off = (off + bytes + 255) & ~(size_t)255;
        return p;
    };
    float* dinv   = (float*)alloc((size_t)N * 4);
    int*   hist   = (int*)alloc((size_t)SCB * NB * 4);   // per-block bucket bases
    int*   bcnt   = (int*)alloc((size_t)NB * 4);
    int*   bstart = (int*)alloc((size_t)(NB + 1) * 4);
    u32*   ebuf   = (u32*)alloc((size_t)E * 4);          // bucketized packed edges
    u32*   glrows = (u32*)alloc((size_t)E * 4);          // global CSR source ids
    int*   goffs  = (int*)alloc((size_t)(N + 1) * 4);    // global CSR offsets
    u16*   bufM   = (u16*)alloc((size_t)N * HID * 2);    // m' (bf16, dinv-scaled)
    u16*   aggB1  = (u16*)alloc((size_t)N * HID * 2);    // agg1 bf16, reused as agg3
    u16*   aggB2  = (u16*)alloc((size_t)N * HID * 2);    // agg2 bf16
    float* stats  = (float*)alloc(3 * 128 * 4);
    float* pooled = (float*)alloc((size_t)NG * HID * 4);
    float* gcnt   = (float*)alloc((size_t)NG * 4);
    (void)ws_size; (void)in_sizes; (void)n_in; (void)out_size;

    u16* aggB3 = aggB1;  // agg1 last read in k_gemm3, before layer-3 agg

    hipMemsetAsync(stats, 0, 3 * 128 * 4, stream);
    hipMemsetAsync(pooled, 0, (size_t)NG * HID * 4, stream);
    hipMemsetAsync(gcnt, 0, (size_t)NG * 4, stream);

    const int nbNode16 = (N + 15) / 16;    // 6250
    const int nbB = (NB + 255) / 256;      // 7

    // graph build: multisplit with private regions, then one global CSR
    k_hist<<<SCB, 256, 0, stream>>>(ecol, hist, E);
    k_btot<<<nbB, 256, 0, stream>>>(hist, bcnt);
    k_bscan<<<1, 256, 0, stream>>>(bcnt, bstart, NB, E);
    k_hcol<<<nbB, 256, 0, stream>>>(hist, bstart);
    k_scatter<<<SCB, 256, 0, stream>>>(erow, ecol, hist, ebuf, E);
    k_csr<<<NB, 256, 0, stream>>>(ebuf, bstart, glrows, goffs, dinv, N);

    // layer 1
    k_gemm<INDIM><<<nbNode16, 256, 0, stream>>>(x, w1, dinv, bufM, N);
    k_agg<<<NB, 256, 0, stream>>>(bufM, dinv, glrows, goffs, aggB1, stats, N);

    // layer 2 (gemm stages relu(BN1(agg1)))
    k_gemm2<<<nbNode16, 256, 0, stream>>>(aggB1, w2, dinv, bufM, N,
                                          stats, g1, be1);
    k_agg<<<NB, 256, 0, stream>>>(bufM, dinv, glrows, goffs, aggB2, stats + 128, N);

    // layer 3 (gemm stages h2 = relu(BN2(agg2) + relu(BN1(agg1))))
    k_gemm3<<<nbNode16, 256, 0, stream>>>(aggB1, aggB2, stats, stats + 128,
                                          g1, be1, g2, be2, w3, dinv, bufM, N);
    k_agg<<<NB, 256, 0, stream>>>(bufM, dinv, glrows, goffs, aggB3, stats + 256, N);

    // pool (BN3+relu inline) + final
    k_pool<<<(N + 63) / 64, 64, 0, stream>>>(aggB3, stats + 256, g3, be3,
                                             batch, pooled, gcnt, N);
    k_final<<<(NG * 64) / 256, 256, 0, stream>>>(pooled, gcnt, fcw, fcb, out);
}